// Round 1
// baseline (1116.263 us; speedup 1.0000x reference)
//
#include <hip/hip_runtime.h>

// Problem constants
#define NB 16
#define NC 64
#define NN 4096
#define ND 8

// Attention tiling
#define TQ 128              // queries per block (= block threads)
#define TK 32               // keys per tile
#define NTILE (NN / TK)     // 128
#define VPAD 4              // vt row stride 68 floats: keeps float4 16B-aligned, <=2-way read conflicts

// Workspace layout (floats):
//   q  : [B][8][N]   at QOFF
//   kT : [B][N][8]   at KOFF   (contiguous 8 floats per key -> wave-uniform scalar loads)
//   v  : [B][64][N]  at VOFF
#define QOFF 0
#define KOFF ((size_t)NB * ND * NN)              // 524288
#define VOFF ((size_t)(2 * NB * ND * NN))        // 1048576

// ---------------- Kernel 1: fused QKV projection ----------------
// grid 256 blocks x 256 threads; thread owns one column n, computes all 80 outputs.
// W reads are wave-uniform -> compiler emits scalar loads (SGPR broadcast into v_fma).
__global__ __launch_bounds__(256) void qkv_kernel(
    const float* __restrict__ x,
    const float* __restrict__ Wq,
    const float* __restrict__ Wk,
    const float* __restrict__ Wv,
    float* __restrict__ q,
    float* __restrict__ kT,
    float* __restrict__ v)
{
    const int tid = threadIdx.x;
    const int blk = blockIdx.x;          // 0..255
    const int b   = blk >> 4;
    const int n   = (blk & 15) * 256 + tid;

    const float* xb = x + (size_t)b * NC * NN + n;
    float xr[NC];
#pragma unroll
    for (int c = 0; c < NC; ++c) xr[c] = xb[(size_t)c * NN];

    // q rows
#pragma unroll
    for (int d = 0; d < ND; ++d) {
        float acc = 0.f;
#pragma unroll
        for (int c = 0; c < NC; ++c) acc = fmaf(Wq[d * NC + c], xr[c], acc);
        q[((size_t)b * ND + d) * NN + n] = acc;
    }

    // k rows -> kT[b][n][d]
    float ka[ND];
#pragma unroll
    for (int d = 0; d < ND; ++d) {
        float acc = 0.f;
#pragma unroll
        for (int c = 0; c < NC; ++c) acc = fmaf(Wk[d * NC + c], xr[c], acc);
        ka[d] = acc;
    }
    float4* kp = (float4*)(kT + ((size_t)b * NN + n) * ND);
    kp[0] = make_float4(ka[0], ka[1], ka[2], ka[3]);
    kp[1] = make_float4(ka[4], ka[5], ka[6], ka[7]);

    // v rows
#pragma unroll 8
    for (int e = 0; e < NC; ++e) {
        float acc = 0.f;
#pragma unroll
        for (int c = 0; c < NC; ++c) acc = fmaf(Wv[e * NC + c], xr[c], acc);
        v[((size_t)b * NC + e) * NN + n] = acc;
    }
}

// ---------------- Kernel 2: flash attention + residual ----------------
// grid 512 blocks x 128 threads. Block = (batch b, query tile qt of 128 queries).
// Score phase: thread t owns query t (online softmax thread-local).
// PV phase: thread owns 8 channels x 8 queries register tile.
__global__ __launch_bounds__(TQ) void attn_kernel(
    const float* __restrict__ x,
    const float* __restrict__ gamma,
    const float* __restrict__ q,
    const float* __restrict__ kT,
    const float* __restrict__ v,
    float* __restrict__ out)
{
    __shared__ __attribute__((aligned(16))) float p_s[TK][TQ];            // 16 KB, p[j][i]
    __shared__ __attribute__((aligned(16))) float vt_s[2][TK][NC + VPAD]; // 17.4 KB, v^T tiles
    __shared__ __attribute__((aligned(16))) float r_s[TQ];
    __shared__ __attribute__((aligned(16))) float l_s[TQ];

    const int tid = threadIdx.x;

    // Bijective XCD swizzle (512 % 8 == 0): XCD x gets contiguous virt range -> 2 batches/XCD in L2
    const int blk0 = blockIdx.x;
    const int virt = (blk0 & 7) * 64 + (blk0 >> 3);
    const int b  = virt >> 5;   // 32 query-tiles per batch
    const int qt = virt & 31;

    // this thread's query vector (score phase)
    const float* qb = q + (size_t)b * ND * NN + (size_t)qt * TQ + tid;
    float qv[ND];
#pragma unroll
    for (int d = 0; d < ND; ++d) qv[d] = qb[(size_t)d * NN];

    const float* kb = kT + (size_t)b * NN * ND;
    const float* vb = v  + (size_t)b * NC * NN;

    // PV mapping: 8 channel-groups x 16 query-groups
    const int ci8 = (tid & 7) * 8;
    const int qi8 = (tid >> 3) * 8;

    float acc[8][8];
#pragma unroll
    for (int cc = 0; cc < 8; ++cc)
#pragma unroll
        for (int ii = 0; ii < 8; ++ii) acc[cc][ii] = 0.f;

    float m = -__builtin_inff();
    float l = 0.f;

    // ---- stage tile 0 into vt_s[0] (transpose v[c][j] -> vt[j][c]) ----
    float vstage[16];
#pragma unroll
    for (int rep = 0; rep < 16; ++rep) {
        const int idx = rep * TQ + tid;
        const int j = idx & (TK - 1);
        const int c = idx >> 5;
        vstage[rep] = vb[(size_t)c * NN + j];
    }
#pragma unroll
    for (int rep = 0; rep < 16; ++rep) {
        const int idx = rep * TQ + tid;
        const int j = idx & (TK - 1);
        const int c = idx >> 5;
        vt_s[0][j][c] = vstage[rep];
    }
    __syncthreads();

    for (int t = 0; t < NTILE; ++t) {
        const int cur = t & 1;
        const bool pf = (t + 1 < NTILE);

        // prefetch next V tile into registers (latency hidden under score+PV)
        if (pf) {
            const float* vsrc = vb + (size_t)(t + 1) * TK;
#pragma unroll
            for (int rep = 0; rep < 16; ++rep) {
                const int idx = rep * TQ + tid;
                const int j = idx & (TK - 1);
                const int c = idx >> 5;
                vstage[rep] = vsrc[(size_t)c * NN + j];
            }
        }

        // ---- score phase: s[j] = q_i . k_j  (k via wave-uniform loads -> scalar cache) ----
        const float* kt = kb + (size_t)t * TK * ND;
        float s[TK];
#pragma unroll
        for (int j = 0; j < TK; ++j) {
            const float4 k0 = *(const float4*)(kt + j * ND);
            const float4 k1 = *(const float4*)(kt + j * ND + 4);
            float a;
            a = k0.x * qv[0];
            a = fmaf(k0.y, qv[1], a);
            a = fmaf(k0.z, qv[2], a);
            a = fmaf(k0.w, qv[3], a);
            a = fmaf(k1.x, qv[4], a);
            a = fmaf(k1.y, qv[5], a);
            a = fmaf(k1.z, qv[6], a);
            a = fmaf(k1.w, qv[7], a);
            s[j] = a;
        }
        float mt = s[0];
#pragma unroll
        for (int j = 1; j < TK; ++j) mt = fmaxf(mt, s[j]);
        const float mnew = fmaxf(m, mt);
        const float rr = __expf(m - mnew);   // m=-inf first iter -> rr=0
        float lsum = 0.f;
#pragma unroll
        for (int j = 0; j < TK; ++j) {
            const float pv = __expf(s[j] - mnew);
            p_s[j][tid] = pv;                 // coalesced LDS write (lane==i)
            lsum += pv;
        }
        l = l * rr + lsum;
        m = mnew;
        r_s[tid] = rr;
        __syncthreads();   // A: p, r ready for PV

        // ---- PV phase: acc[c][i] = acc*r + sum_j p[j][i] * vt[j][c] ----
        {
            const float4 ra = *(const float4*)&r_s[qi8];
            const float4 rb = *(const float4*)&r_s[qi8 + 4];
            const float rq[8] = {ra.x, ra.y, ra.z, ra.w, rb.x, rb.y, rb.z, rb.w};
#pragma unroll
            for (int cc = 0; cc < 8; ++cc)
#pragma unroll
                for (int ii = 0; ii < 8; ++ii) acc[cc][ii] *= rq[ii];
        }
#pragma unroll 8
        for (int j = 0; j < TK; ++j) {
            const float4 p0 = *(const float4*)&p_s[j][qi8];
            const float4 p1 = *(const float4*)&p_s[j][qi8 + 4];
            const float4 v0 = *(const float4*)&vt_s[cur][j][ci8];
            const float4 v1 = *(const float4*)&vt_s[cur][j][ci8 + 4];
            const float pj[8] = {p0.x, p0.y, p0.z, p0.w, p1.x, p1.y, p1.z, p1.w};
            const float vj[8] = {v0.x, v0.y, v0.z, v0.w, v1.x, v1.y, v1.z, v1.w};
#pragma unroll
            for (int cc = 0; cc < 8; ++cc)
#pragma unroll
                for (int ii = 0; ii < 8; ++ii)
                    acc[cc][ii] = fmaf(vj[cc], pj[ii], acc[cc][ii]);
        }

        // write prefetched tile to the other LDS buffer (no hazard with concurrent PV reads)
        if (pf) {
#pragma unroll
            for (int rep = 0; rep < 16; ++rep) {
                const int idx = rep * TQ + tid;
                const int j = idx & (TK - 1);
                const int c = idx >> 5;
                vt_s[cur ^ 1][j][c] = vstage[rep];
            }
        }
        __syncthreads();   // B: PV done everywhere (p_s free), next vt buffer complete
    }

    l_s[tid] = l;
    __syncthreads();

    // ---- epilogue: out = x + gamma * acc / l ----
    const float g = gamma[0];
    float li[8];
    {
        const float4 la = *(const float4*)&l_s[qi8];
        const float4 lb = *(const float4*)&l_s[qi8 + 4];
        li[0] = 1.f / la.x; li[1] = 1.f / la.y; li[2] = 1.f / la.z; li[3] = 1.f / la.w;
        li[4] = 1.f / lb.x; li[5] = 1.f / lb.y; li[6] = 1.f / lb.z; li[7] = 1.f / lb.w;
    }
    const int gi0 = qt * TQ + qi8;
#pragma unroll
    for (int cc = 0; cc < 8; ++cc) {
        const int c = ci8 + cc;
        const float* xp = x   + ((size_t)b * NC + c) * NN + gi0;
        float*       op = out + ((size_t)b * NC + c) * NN + gi0;
        const float4 x0 = *(const float4*)xp;
        const float4 x1 = *(const float4*)(xp + 4);
        float4 o0, o1;
        o0.x = fmaf(g, acc[cc][0] * li[0], x0.x);
        o0.y = fmaf(g, acc[cc][1] * li[1], x0.y);
        o0.z = fmaf(g, acc[cc][2] * li[2], x0.z);
        o0.w = fmaf(g, acc[cc][3] * li[3], x0.w);
        o1.x = fmaf(g, acc[cc][4] * li[4], x1.x);
        o1.y = fmaf(g, acc[cc][5] * li[5], x1.y);
        o1.z = fmaf(g, acc[cc][6] * li[6], x1.z);
        o1.w = fmaf(g, acc[cc][7] * li[7], x1.w);
        *(float4*)op       = o0;
        *(float4*)(op + 4) = o1;
    }
}

extern "C" void kernel_launch(void* const* d_in, const int* in_sizes, int n_in,
                              void* d_out, int out_size, void* d_ws, size_t ws_size,
                              hipStream_t stream) {
    const float* x     = (const float*)d_in[0];
    const float* Wq    = (const float*)d_in[1];
    const float* Wk    = (const float*)d_in[2];
    const float* Wv    = (const float*)d_in[3];
    const float* gamma = (const float*)d_in[4];
    float* out = (float*)d_out;
    float* ws  = (float*)d_ws;

    float* q  = ws + QOFF;
    float* kT = ws + KOFF;
    float* v  = ws + VOFF;

    qkv_kernel<<<dim3(NB * (NN / 256)), dim3(256), 0, stream>>>(x, Wq, Wk, Wv, q, kT, v);
    attn_kernel<<<dim3(NB * (NN / TQ)), dim3(TQ), 0, stream>>>(x, gamma, q, kT, v, out);
}

// Round 8
// 241.063 us; speedup vs baseline: 4.6306x; 4.6306x over previous
//
#include <hip/hip_runtime.h>

#define NB 16
#define NC 64
#define NN 4096

typedef _Float16 half8 __attribute__((ext_vector_type(8)));
typedef float f32x16 __attribute__((ext_vector_type(16)));
typedef unsigned int uint4v __attribute__((ext_vector_type(4)));

#define MFMA(A, B, C) __builtin_amdgcn_mfma_f32_32x32x16_f16(A, B, C, 0, 0, 0)

// Workspace layout, in _Float16 units:
//   qT: [B][N][16]  (qhi[8], qlo[8])   -> 16*4096*16 = 1,048,576 halves
//   kT: [B][N][16]  (khi[8], klo[8])   -> 1,048,576 halves
//   vh: [B][C][N]                      -> 4,194,304 halves
// total 12.6 MB.
#define QT_OFF ((size_t)0)
#define KT_OFF ((size_t)NB * NN * 16)
#define VH_OFF ((size_t)2 * NB * NN * 16)

// ---------------- Kernel 1: fused QKV projection (f16 outputs, hi/lo q,k) ----
// grid (256, 2) x 256 threads. Thread owns column n. sel=0: q,k,v[0:24); sel=1: v[24:64).
__global__ __launch_bounds__(256) void qkv_kernel(
    const float* __restrict__ x, const float* __restrict__ Wq,
    const float* __restrict__ Wk, const float* __restrict__ Wv,
    _Float16* __restrict__ qT, _Float16* __restrict__ kT, _Float16* __restrict__ vh)
{
    const int tid = threadIdx.x;
    const int blk = blockIdx.x;
    const int sel = blockIdx.y;
    const int b = blk >> 4;
    const int n = (blk & 15) * 256 + tid;

    const float* xb = x + (size_t)b * NC * NN + n;
    float xr[NC];
#pragma unroll
    for (int c = 0; c < NC; ++c) xr[c] = xb[(size_t)c * NN];

    if (sel == 0) {
        float qa[8], ka[8];
#pragma unroll
        for (int d = 0; d < 8; ++d) {
            float aq = 0.f, ak = 0.f;
#pragma unroll
            for (int c = 0; c < NC; ++c) {
                aq = fmaf(Wq[d * NC + c], xr[c], aq);
                ak = fmaf(Wk[d * NC + c], xr[c], ak);
            }
            qa[d] = aq; ka[d] = ak;
        }
        half8 qhi, qlo, khi, klo;
#pragma unroll
        for (int d = 0; d < 8; ++d) {
            _Float16 hq = (_Float16)qa[d];
            qhi[d] = hq; qlo[d] = (_Float16)(qa[d] - (float)hq);
            _Float16 hk = (_Float16)ka[d];
            khi[d] = hk; klo[d] = (_Float16)(ka[d] - (float)hk);
        }
        _Float16* qr = qT + ((size_t)b * NN + n) * 16;
        *(half8*)qr = qhi; *(half8*)(qr + 8) = qlo;
        _Float16* kr = kT + ((size_t)b * NN + n) * 16;
        *(half8*)kr = khi; *(half8*)(kr + 8) = klo;
#pragma unroll 4
        for (int e = 0; e < 24; ++e) {
            float a = 0.f;
#pragma unroll
            for (int c = 0; c < NC; ++c) a = fmaf(Wv[e * NC + c], xr[c], a);
            vh[((size_t)b * NC + e) * NN + n] = (_Float16)a;
        }
    } else {
#pragma unroll 4
        for (int e = 24; e < 64; ++e) {
            float a = 0.f;
#pragma unroll
            for (int c = 0; c < NC; ++c) a = fmaf(Wv[e * NC + c], xr[c], a);
            vh[((size_t)b * NC + e) * NN + n] = (_Float16)a;
        }
    }
}

// ---------------- Kernel 2: MFMA flash attention + residual ----------------
// grid 512 x 256. 4 waves/block, each wave owns 32 queries, loops 128 key-tiles of 32.
// Swapped score MFMA (M=keys,N=queries): lane's 16 D-regs = P for query (lane&31);
// PV B-frag rebuilt in-register via cvt_pkrtz + permlane32_swap. No LDS, no barriers.
__global__ __launch_bounds__(256) void attn_kernel(
    const float* __restrict__ x, const float* __restrict__ gamma,
    const _Float16* __restrict__ qT, const _Float16* __restrict__ kT,
    const _Float16* __restrict__ vh, float* __restrict__ out)
{
    const int tid  = threadIdx.x;
    const int lane = tid & 63;
    const int wid  = tid >> 6;
    const int l31  = lane & 31;
    const int g    = lane >> 5;

    // bijective XCD swizzle (512 % 8 == 0): contiguous virt per XCD -> K/V L2 locality
    const int blk  = blockIdx.x;
    const int virt = (blk & 7) * 64 + (blk >> 3);
    const int b    = virt >> 5;
    const int qt   = virt & 31;
    const int q    = qt * 128 + wid * 32 + l31;

    // Q B-frags (loop-invariant). B1 = [qhi;qhi], B2 = [qlo;0].
    const _Float16* qr = qT + ((size_t)b * NN + q) * 16;
    const half8 qb1 = *(const half8*)qr;
    const half8 qlo = *(const half8*)(qr + 8);
    half8 qb2;
#pragma unroll
    for (int i = 0; i < 8; ++i) qb2[i] = g ? (_Float16)0 : qlo[i];

    // K A-frag pointer: lane reads [khi(0:8)] (g=0) or [klo(0:8)] (g=1) of key t*32+l31
    const _Float16* kp  = kT + (size_t)b * NN * 16 + (size_t)l31 * 16 + (size_t)g * 8;
    // V A-frag pointers: row c = mt*32 + l31, cols t*32 + kt*16 + g*8
    const _Float16* vp0 = vh + (size_t)b * NC * NN + (size_t)l31 * NN + (size_t)g * 8;
    const _Float16* vp1 = vp0 + (size_t)32 * NN;

    f32x16 acc0 = {}, acc1 = {};
    float mrun = -__builtin_inff();
    float lrun = 0.f;

    half8 ka = *(const half8*)kp;   // K frag, tile 0

    for (int t = 0; t < NN / 32; ++t) {
        const int off = t * 32;
        // V A-frags for this tile — issue early, consumed after softmax (~200cy cover)
        const half8 va00 = *(const half8*)(vp0 + off);
        const half8 va01 = *(const half8*)(vp0 + off + 16);
        const half8 va10 = *(const half8*)(vp1 + off);
        const half8 va11 = *(const half8*)(vp1 + off + 16);

        // scores: S[key][q] = khi*qhi + klo*qhi + khi*qlo  (fp32-accurate)
        f32x16 S = {};
        S = MFMA(ka, qb1, S);
        S = MFMA(ka, qb2, S);

        // prefetch next K frag (consumed next iter)
        const int tn = (t + 1 < NN / 32) ? (t + 1) : t;
        ka = *(const half8*)(kp + (size_t)tn * 512);

        const float s0 = S[0],  s1 = S[1],  s2 = S[2],  s3 = S[3];
        const float s4 = S[4],  s5 = S[5],  s6 = S[6],  s7 = S[7];
        const float s8 = S[8],  s9 = S[9],  s10 = S[10], s11 = S[11];
        const float s12 = S[12], s13 = S[13], s14 = S[14], s15 = S[15];

        // row max (16 regs + cross-half swap)
        float pmax = fmaxf(
            fmaxf(fmaxf(fmaxf(s0, s1), fmaxf(s2, s3)), fmaxf(fmaxf(s4, s5), fmaxf(s6, s7))),
            fmaxf(fmaxf(fmaxf(s8, s9), fmaxf(s10, s11)), fmaxf(fmaxf(s12, s13), fmaxf(s14, s15))));
        pmax = fmaxf(pmax, __shfl_xor(pmax, 32, 64));

        // defer-max: only rescale when some query's max grew by > 8
        if (__any(pmax > mrun + 8.0f)) {
            const float mnew = fmaxf(mrun, pmax);
            const float rs = __expf(mrun - mnew);   // first tile: exp(-inf) = 0
            lrun *= rs;
#pragma unroll
            for (int r = 0; r < 16; ++r) { acc0[r] *= rs; acc1[r] *= rs; }
            mrun = mnew;
        }

        const float p0 = __expf(s0 - mrun),  p1 = __expf(s1 - mrun);
        const float p2 = __expf(s2 - mrun),  p3 = __expf(s3 - mrun);
        const float p4 = __expf(s4 - mrun),  p5 = __expf(s5 - mrun);
        const float p6 = __expf(s6 - mrun),  p7 = __expf(s7 - mrun);
        const float p8 = __expf(s8 - mrun),  p9 = __expf(s9 - mrun);
        const float p10 = __expf(s10 - mrun), p11 = __expf(s11 - mrun);
        const float p12 = __expf(s12 - mrun), p13 = __expf(s13 - mrun);
        const float p14 = __expf(s14 - mrun), p15 = __expf(s15 - mrun);

        float ls = (((p0 + p1) + (p2 + p3)) + ((p4 + p5) + (p6 + p7)))
                 + (((p8 + p9) + (p10 + p11)) + ((p12 + p13) + (p14 + p15)));
        ls += __shfl_xor(ls, 32, 64);
        lrun += ls;

        // pack P to f16 pairs; xN at lane (g,l31) holds key-pairs:
        //   x0=(0,1)+4g  x1=(2,3)+4g  x2=(8,9)+4g  x3=(10,11)+4g
        //   x4=(16,17)+4g x5=(18,19)+4g x6=(24,25)+4g x7=(26,27)+4g
        const unsigned int x0 = __builtin_bit_cast(unsigned int, __builtin_amdgcn_cvt_pkrtz(p0, p1));
        const unsigned int x1 = __builtin_bit_cast(unsigned int, __builtin_amdgcn_cvt_pkrtz(p2, p3));
        const unsigned int x2 = __builtin_bit_cast(unsigned int, __builtin_amdgcn_cvt_pkrtz(p4, p5));
        const unsigned int x3 = __builtin_bit_cast(unsigned int, __builtin_amdgcn_cvt_pkrtz(p6, p7));
        const unsigned int x4 = __builtin_bit_cast(unsigned int, __builtin_amdgcn_cvt_pkrtz(p8, p9));
        const unsigned int x5 = __builtin_bit_cast(unsigned int, __builtin_amdgcn_cvt_pkrtz(p10, p11));
        const unsigned int x6 = __builtin_bit_cast(unsigned int, __builtin_amdgcn_cvt_pkrtz(p12, p13));
        const unsigned int x7 = __builtin_bit_cast(unsigned int, __builtin_amdgcn_cvt_pkrtz(p14, p15));

        // cross-half exchange -> B-frags (uint_e = keys (8g+2e, 8g+2e+1)).
        // swap(A,B): out0 = {A@g0 | B_g0@g1}, out1 = {A_g1@g0 | B@g1}  (T12 order)
        auto r0 = __builtin_amdgcn_permlane32_swap(x0, x2, false, false);
        auto r1 = __builtin_amdgcn_permlane32_swap(x1, x3, false, false);
        auto r2 = __builtin_amdgcn_permlane32_swap(x4, x6, false, false);
        auto r3 = __builtin_amdgcn_permlane32_swap(x5, x7, false, false);
        const uint4v w0 = {(unsigned int)r0[0], (unsigned int)r1[0],
                           (unsigned int)r0[1], (unsigned int)r1[1]};   // keys 0..15
        const uint4v w1 = {(unsigned int)r2[0], (unsigned int)r3[0],
                           (unsigned int)r2[1], (unsigned int)r3[1]};   // keys 16..31
        const half8 pv0 = __builtin_bit_cast(half8, w0);
        const half8 pv1 = __builtin_bit_cast(half8, w1);

        // PV: out[c][q] += V[c][k] * P[k][q]
        acc0 = MFMA(va00, pv0, acc0);
        acc0 = MFMA(va01, pv1, acc0);
        acc1 = MFMA(va10, pv0, acc1);
        acc1 = MFMA(va11, pv1, acc1);
    }

    // epilogue: out = x + gamma * acc / l
    const float linv = 1.0f / lrun;
    const float gm = gamma[0];
#pragma unroll
    for (int r = 0; r < 16; ++r) {
        const int crow = (r & 3) + 8 * (r >> 2) + 4 * g;
        const size_t i0 = ((size_t)b * NC + crow) * NN + q;
        out[i0] = fmaf(gm, acc0[r] * linv, x[i0]);
        const size_t i1 = ((size_t)b * NC + crow + 32) * NN + q;
        out[i1] = fmaf(gm, acc1[r] * linv, x[i1]);
    }
}

extern "C" void kernel_launch(void* const* d_in, const int* in_sizes, int n_in,
                              void* d_out, int out_size, void* d_ws, size_t ws_size,
                              hipStream_t stream) {
    const float* x     = (const float*)d_in[0];
    const float* Wq    = (const float*)d_in[1];
    const float* Wk    = (const float*)d_in[2];
    const float* Wv    = (const float*)d_in[3];
    const float* gamma = (const float*)d_in[4];
    float* out = (float*)d_out;
    _Float16* ws = (_Float16*)d_ws;

    _Float16* qT = ws + QT_OFF;
    _Float16* kT = ws + KT_OFF;
    _Float16* vh = ws + VH_OFF;

    qkv_kernel<<<dim3(NB * (NN / 256), 2), dim3(256), 0, stream>>>(x, Wq, Wk, Wv, qT, kT, vh);
    attn_kernel<<<dim3(NB * (NN / 128)), dim3(256), 0, stream>>>(x, gamma, qT, kT, vh, out);
}